// Round 8
// baseline (583.437 us; speedup 1.0000x reference)
//
#include <hip/hip_runtime.h>

// SNN: 2-layer LIF, T=4096, B=1024, 6->10->27.
// Round 8: ZERO-LDS, ZERO-BARRIER, single wave per element, issue-bound design.
//   Rationale: 1024 independent chains = 1 chain/SIMD hard cap; stalls can't be
//   hidden (R2/R4/R5/R6 data), so eliminate them. No DS ops in the main loop at all.
//   - x staged lane-per-timestep (coalesced, 1-chunk prefetch), broadcast per step
//     via v_readlane with IMMEDIATE lane index (64-step fully-unrolled body)
//   - lane i<10 = layer-1 neuron: 6-fma dot (SGPR x operands) + mem1 chain
//   - ballot -> wave-uniform 10-bit mask (SGPR)
//   - lane j<27 = layer-2 neuron: cur2 = b2 + sum bit_i(m)*W2[j][i] as 10 fmacs
//     with SALU-selected {0,1} multipliers (replaces LDS tables)
//   - mem2 chain in the same wave; spectator lanes mirror clamped rows (harmless)
// Per-element arithmetic: same mul/fma/add order for layer 1 and chains as rounds
// 1-7 (absmax 0.0); layer-2 summation is b2 + ascending-i conditional fmas.

#define T_STEPS 4096
#define BETA 0.9f
#define THRESH 1.0f
#define CH 64
#define NCHUNK (T_STEPS / CH)   // 64

__device__ __forceinline__ float lane_bcast(float v, int lane) {
    return __int_as_float(__builtin_amdgcn_readlane(__float_as_int(v), lane));
}

__global__ __launch_bounds__(64, 1) void snn_kernel(
    const float* __restrict__ x,   // [B][6][T]
    const float* __restrict__ W1,  // [10][6]
    const float* __restrict__ b1,  // [10]
    const float* __restrict__ W2,  // [27][10]
    const float* __restrict__ b2,  // [27]
    float* __restrict__ out)       // [B][27]
{
    const int l = threadIdx.x;
    const int b = blockIdx.x;

    const int ri = (l < 10) ? l : 9;    // layer-1 neuron owned (spectators mirror 9)
    const int rj = (l < 27) ? l : 26;   // layer-2 neuron owned (spectators mirror 26)

    // ---- per-lane weights in registers (loaded once) ----
    float w1row[6];                     // W1[ri][*]
    #pragma unroll
    for (int c = 0; c < 6; ++c) w1row[c] = W1[ri * 6 + c];
    const float b1i = b1[ri];

    float w2c[10];                      // W2[rj][*]
    #pragma unroll
    for (int i = 0; i < 10; ++i) w2c[i] = W2[rj * 10 + i];
    const float b2j = b2[rj];

    // ---- state ----
    float mem1 = 0.0f, mem2 = 0.0f;
    bool  sp1 = false, sp2 = false;

    // ---- x staging: lane t holds x[c][chunk*64+t]; prefetch one chunk ahead ----
    const float* xb = x + (size_t)b * 6 * T_STEPS;
    float xv[6], xn[6];
    #pragma unroll
    for (int c = 0; c < 6; ++c) xv[c] = xb[c * T_STEPS + l];

    #pragma unroll 1
    for (int k = 0; k < NCHUNK; ++k) {
        if (k + 1 < NCHUNK) {
            #pragma unroll
            for (int c = 0; c < 6; ++c) xn[c] = xb[c * T_STEPS + (k + 1) * CH + l];
        }

        #pragma unroll
        for (int s = 0; s < CH; ++s) {
            // broadcast step-s inputs (immediate-lane readlane -> uniform scalars)
            const float x0 = lane_bcast(xv[0], s);
            const float x1 = lane_bcast(xv[1], s);
            const float x2 = lane_bcast(xv[2], s);
            const float x3 = lane_bcast(xv[3], s);
            const float x4 = lane_bcast(xv[4], s);
            const float x5 = lane_bcast(xv[5], s);

            // layer-1 current (same op order as rounds 1-7)
            float acc = x0 * w1row[0];
            acc = fmaf(x1, w1row[1], acc);
            acc = fmaf(x2, w1row[2], acc);
            acc = fmaf(x3, w1row[3], acc);
            acc = fmaf(x4, w1row[4], acc);
            acc = fmaf(x5, w1row[5], acc);
            const float c1 = acc + b1i;

            // mem1 chain
            float t1 = fmaf(BETA, mem1, c1);
            mem1 = sp1 ? (t1 - THRESH) : t1;       // == t1 - rst*THRESH
            sp1 = mem1 > THRESH;

            // spike mask, wave-uniform SGPR (bits 10+ mirror bit 9; masked off)
            const unsigned m = (unsigned)__ballot(sp1) & 0x3FFu;

            // layer-2 current: b2 + ascending conditional adds of W2[j][i]
            float cur2 = fmaf((m & 1u)         ? 1.0f : 0.0f, w2c[0], b2j);
            cur2 = fmaf(((m >> 1) & 1u) ? 1.0f : 0.0f, w2c[1], cur2);
            cur2 = fmaf(((m >> 2) & 1u) ? 1.0f : 0.0f, w2c[2], cur2);
            cur2 = fmaf(((m >> 3) & 1u) ? 1.0f : 0.0f, w2c[3], cur2);
            cur2 = fmaf(((m >> 4) & 1u) ? 1.0f : 0.0f, w2c[4], cur2);
            cur2 = fmaf(((m >> 5) & 1u) ? 1.0f : 0.0f, w2c[5], cur2);
            cur2 = fmaf(((m >> 6) & 1u) ? 1.0f : 0.0f, w2c[6], cur2);
            cur2 = fmaf(((m >> 7) & 1u) ? 1.0f : 0.0f, w2c[7], cur2);
            cur2 = fmaf(((m >> 8) & 1u) ? 1.0f : 0.0f, w2c[8], cur2);
            cur2 = fmaf(((m >> 9) & 1u) ? 1.0f : 0.0f, w2c[9], cur2);

            // mem2 chain
            float t2 = fmaf(BETA, mem2, cur2);
            mem2 = sp2 ? (t2 - THRESH) : t2;
            sp2 = mem2 > THRESH;
        }

        if (k + 1 < NCHUNK) {
            #pragma unroll
            for (int c = 0; c < 6; ++c) xv[c] = xn[c];
        }
    }

    if (l < 27) {
        out[b * 27 + l] = sp2 ? 1.0f : 0.0f;
    }
}

extern "C" void kernel_launch(void* const* d_in, const int* in_sizes, int n_in,
                              void* d_out, int out_size, void* d_ws, size_t ws_size,
                              hipStream_t stream) {
    const float* x  = (const float*)d_in[0];
    const float* W1 = (const float*)d_in[1];
    const float* b1 = (const float*)d_in[2];
    const float* W2 = (const float*)d_in[3];
    const float* b2 = (const float*)d_in[4];
    float* out = (float*)d_out;

    const int B = in_sizes[0] / (6 * T_STEPS);  // 1024
    snn_kernel<<<dim3(B), dim3(64), 0, stream>>>(x, W1, b1, W2, b2, out);
}